// Round 11
// baseline (547.061 us; speedup 1.0000x reference)
//
#include <hip/hip_runtime.h>
#include <hip/hip_bf16.h>
#include <hip/hip_cooperative_groups.h>
#include <cstdint>
#include <cstddef>

namespace cg = cooperative_groups;

#define NN 50000
#define NE 800000
#define EPS 1e-5f

typedef short bf16x8 __attribute__((ext_vector_type(8)));
typedef float f32x4  __attribute__((ext_vector_type(4)));
typedef float f32x2  __attribute__((ext_vector_type(2)));

// ---------------- ws layout (bytes) ----------------
// H8    :          0   25,600,000  uchar   H[n][s][co] fp8 e4m3
// Hroot : 25,600,000   12,800,000  float   (x@root)[n][co]
// ESRC  : 38,400,000    3,200,000  int     src per edge (dst-sorted)
// EW8H  : 41,600,000   12,800,000  ushort  8 bf16 weights per edge (dst-sorted)
// OFFS  : 54,400,000      200,064  int     GLOBAL CSR offsets [NN+1]
// PART  : 54,600,064          128  int     scan partials
// BNPS  : 54,600,192       16,384  float   BN sum partials
// BNPQ  : 54,616,576       16,384  float   BN ssq partials
// WTG   : 54,632,960       73,728  ushort  WTg[s][co][ci] bf16 (s=8 is root)
// DEG   : 54,706,688      200,000  int     degree histogram

#define NB_MFMA 1564   // 782 x 2 halves
#define NBC 1024       // cooperative blocks
#define NTC 256
#define GSTRIDE (NBC * NTC)   // 262144

static __device__ __forceinline__ ushort f2bf(float f) {
    __hip_bfloat16 h = __float2bfloat16(f);
    return *reinterpret_cast<ushort*>(&h);
}
static __device__ __forceinline__ uint32_t pack2(float a, float b) {
    return (uint32_t)f2bf(a) | ((uint32_t)f2bf(b) << 16);
}

// ---------------------------------------------------------------------------
// K0 (cooperative): zero(deg,bn) + WTg prep | count (rank in regs) |
// scan + globalize offs | scatter. 1024 blocks x 256, 4 blocks/CU guaranteed.
// ---------------------------------------------------------------------------
__global__ __launch_bounds__(NTC, 4) void coop_k(const int* __restrict__ ei,
                                                 const float* __restrict__ attr,
                                                 const float* __restrict__ W,
                                                 const float* __restrict__ root,
                                                 ushort* __restrict__ WTg,
                                                 int* __restrict__ deg,
                                                 int* __restrict__ offs,
                                                 int* __restrict__ part,
                                                 int* __restrict__ esrc,
                                                 ushort* __restrict__ ew8h,
                                                 float* __restrict__ bnps,
                                                 float* __restrict__ bnpq) {
    cg::grid_group grid = cg::this_grid();
    __shared__ int sh[256];
    __shared__ int pp[25];
    const int t = threadIdx.x, b = blockIdx.x;
    const int gtid = b * NTC + t;

    // ---- S0: zero accumulators + WTg transpose ----
    for (int i = gtid; i < NN; i += GSTRIDE) deg[i] = 0;
    for (int i = gtid; i < 4096; i += GSTRIDE) { bnps[i] = 0.f; bnpq[i] = 0.f; }
    for (int i = gtid; i < 9 * 4096; i += GSTRIDE) {
        const int s = i >> 12, co = (i >> 6) & 63, ci = i & 63;
        const float v = (s < 8) ? W[s * 4096 + ci * 64 + co] : root[ci * 64 + co];
        WTg[i] = f2bf(v);
    }
    grid.sync();

    // ---- S1: degree count; keep rank in registers ----
    int rk[4];
    #pragma unroll
    for (int k = 0; k < 4; ++k) {
        const int e = gtid + k * GSTRIDE;
        if (e < NE) rk[k] = atomicAdd(&deg[ei[NE + e]], 1);
    }
    grid.sync();

    // ---- S2a: block-local exclusive scan (blocks 0..24) ----
    if (b < 25) {
        const int base = b * 2048 + t * 8;
        int v[8]; int sum = 0;
        #pragma unroll
        for (int k = 0; k < 8; ++k) {
            int i = base + k;
            int d = (i < NN) ? deg[i] : 0;
            v[k] = sum; sum += d;
        }
        sh[t] = sum; __syncthreads();
        for (int off = 1; off < 256; off <<= 1) {
            int val = sh[t];
            int add = (t >= off) ? sh[t - off] : 0;
            __syncthreads();
            sh[t] = val + add;
            __syncthreads();
        }
        int excl = (t > 0) ? sh[t - 1] : 0;
        #pragma unroll
        for (int k = 0; k < 8; ++k) {
            int i = base + k;
            if (i < NN) offs[i] = excl + v[k];
        }
        if (t == 255) part[b] = sh[255];
    }
    grid.sync();

    // ---- S2b: globalize offs (add block prefix), write sentinel ----
    if (t < 25) pp[t] = part[t];
    __syncthreads();
    if (t == 0) {
        int s = 0;
        #pragma unroll
        for (int i = 0; i < 25; ++i) { int v = pp[i]; pp[i] = s; s += v; }
    }
    __syncthreads();
    for (int i = gtid; i < NN; i += GSTRIDE) offs[i] += pp[i >> 11];
    if (gtid == 0) offs[NN] = NE;
    grid.sync();

    // ---- S3: scatter edges (no atomics): p = offs[dst] + rank ----
    #pragma unroll
    for (int k = 0; k < 4; ++k) {
        const int e = gtid + k * GSTRIDE;
        if (e < NE) {
            const int src = ei[e];
            const int dst = ei[NE + e];
            const float f0 = attr[(size_t)e * 3 + 0];
            const float f1 = attr[(size_t)e * 3 + 1];
            const float f2 = attr[(size_t)e * 3 + 2];
            const float g0 = 1.f - f0, g1 = 1.f - f1, g2 = 1.f - f2;
            const float w00 = g1 * g2, w01 = f1 * g2, w10 = g1 * f2, w11 = f1 * f2;
            const int p = offs[dst] + rk[k];
            esrc[p] = src;
            uint4 u;
            u.x = pack2(g0 * w00, f0 * w00);
            u.y = pack2(g0 * w01, f0 * w01);
            u.z = pack2(g0 * w10, f0 * w10);
            u.w = pack2(g0 * w11, f0 * w11);
            *(uint4*)&ew8h[(size_t)p * 8] = u;
        }
    }
}

// ---------------------------------------------------------------------------
// K1: MFMA GEMM -> H8 (fp8) / Hroot (f32). 16x16x32 bf16, swapped operands
// (D row-dim = co, col-dim = node). Grid 1564: b<782 -> s 0..4, else s 5..8.
// ---------------------------------------------------------------------------
__global__ __launch_bounds__(256) void mfma_k(const float* __restrict__ x,
                                              const ushort* __restrict__ WTg,
                                              uint8_t* __restrict__ H8,
                                              float* __restrict__ Hroot) {
    __shared__ __align__(16) ushort XA[64 * 64];       // 8 KB
    __shared__ __align__(16) ushort WT[5 * 64 * 64];   // 40 KB
    const int t = threadIdx.x;
    const int b = blockIdx.x;
    const int bx   = (b < 782) ? b : b - 782;
    const int half = (b < 782) ? 0 : 1;
    const int n0 = bx * 64;
    const int sbeg   = half ? 5 : 0;
    const int scount = half ? 4 : 5;

    // stage XA[node][ci] bf16, XOR-swizzled, b128 writes
    #pragma unroll
    for (int rep = 0; rep < 2; ++rep) {
        const int vt   = rep * 256 + t;
        const int row  = vt >> 3;          // node local 0..63
        const int col8 = vt & 7;
        const int n = n0 + row;
        uint4 u;
        if (n < NN) {
            const float4 v0 = *(const float4*)&x[(size_t)n * 64 + col8 * 8];
            const float4 v1 = *(const float4*)&x[(size_t)n * 64 + col8 * 8 + 4];
            u.x = pack2(v0.x, v0.y); u.y = pack2(v0.z, v0.w);
            u.z = pack2(v1.x, v1.y); u.w = pack2(v1.z, v1.w);
        } else {
            u = make_uint4(0, 0, 0, 0);
        }
        const int idx = (row * 64 + col8 * 8) ^ ((row & 7) << 3);
        *(uint4*)&XA[idx] = u;
    }
    // stage WT tiles from WTg: b128 copies, swizzled
    const int nchunk = scount * 512;                   // uint4 chunks
    for (int c = t; c < nchunk; c += 256) {
        const int row  = c >> 3;           // slocal*64 + co
        const int col8 = c & 7;
        const uint4 u = *(const uint4*)&WTg[(size_t)(sbeg * 64 + row) * 64 + col8 * 8];
        const int idx = (row * 64 + col8 * 8) ^ ((row & 7) << 3);
        *(uint4*)&WT[idx] = u;
    }
    __syncthreads();

    const int w    = t >> 6;
    const int lane = t & 63;
    const int mrow = lane & 15;
    const int kgrp = lane >> 4;
    const int swz  = (mrow & 7) << 3;
    const int arow = w * 16 + mrow;
    const int n    = n0 + arow;

    const bf16x8 a0 = *(const bf16x8*)&XA[((arow * 64) + 0 * 32 + kgrp * 8) ^ swz];
    const bf16x8 a1 = *(const bf16x8*)&XA[((arow * 64) + 1 * 32 + kgrp * 8) ^ swz];

    for (int sl = 0; sl < scount; ++sl) {
        const int s = sbeg + sl;
        const ushort* wt = &WT[sl * 4096];
        f32x4 acc[4];
        #pragma unroll
        for (int ct = 0; ct < 4; ++ct) {
            acc[ct] = (f32x4){0.f, 0.f, 0.f, 0.f};
            const int brow = ct * 16 + mrow;
            const bf16x8 b0 = *(const bf16x8*)&wt[((brow * 64) + 0 * 32 + kgrp * 8) ^ swz];
            const bf16x8 b1 = *(const bf16x8*)&wt[((brow * 64) + 1 * 32 + kgrp * 8) ^ swz];
            acc[ct] = __builtin_amdgcn_mfma_f32_16x16x32_bf16(b0, a0, acc[ct], 0, 0, 0);
            acc[ct] = __builtin_amdgcn_mfma_f32_16x16x32_bf16(b1, a1, acc[ct], 0, 0, 0);
        }
        if (n < NN) {
            if (s < 8) {
                #pragma unroll
                for (int ct = 0; ct < 4; ++ct) {
                    int p = __builtin_amdgcn_cvt_pk_fp8_f32(acc[ct][0], acc[ct][1], 0, false);
                    p     = __builtin_amdgcn_cvt_pk_fp8_f32(acc[ct][2], acc[ct][3], p, true);
                    *(uint32_t*)&H8[(size_t)n * 512 + s * 64 + ct * 16 + kgrp * 4] = (uint32_t)p;
                }
            } else {
                #pragma unroll
                for (int ct = 0; ct < 4; ++ct) {
                    *(float4*)&Hroot[(size_t)n * 64 + ct * 16 + kgrp * 4] =
                        make_float4(acc[ct][0], acc[ct][1], acc[ct][2], acc[ct][3]);
                }
            }
        }
    }
}

// ---------------------------------------------------------------------------
// K2: gather-aggregate (fp8 H) + fused BN partials. One node per wave.
// lane l: s=l>>3, co=(l&7)*8..+8 -> one dwordx2 (8 fp8) per edge per lane.
// ---------------------------------------------------------------------------
__global__ __launch_bounds__(256) void aggregate_k(const int* __restrict__ offs,
                                                   const int* __restrict__ esrc,
                                                   const ushort* __restrict__ ew8h,
                                                   const uint8_t* __restrict__ H8,
                                                   const float* __restrict__ Hroot,
                                                   float* __restrict__ outb,
                                                   float* __restrict__ bnps,
                                                   float* __restrict__ bnpq) {
    __shared__ float red_s[4][64], red_q[4][64];
    const int t = threadIdx.x, lane = t & 63, w = t >> 6;
    const int n = blockIdx.x * 4 + w;            // NN = 4*12500, no tail
    const int sidx = lane >> 3;
    const int cog  = lane & 7;
    const int beg = offs[n], end = offs[n + 1];
    const int cnt = end - beg;
    const int* sp = esrc + beg;
    const ushort* wp = ew8h + (size_t)beg * 8 + sidx;
    const size_t loff = (size_t)(lane << 3);     // byte offset: s*64 + cog*8

    f32x2 acc2[4] = {(f32x2){0.f, 0.f}, (f32x2){0.f, 0.f},
                     (f32x2){0.f, 0.f}, (f32x2){0.f, 0.f}};

#define ACCUM(wv, h)                                                         \
    {                                                                        \
        const f32x2 w2_ = {wv, wv};                                          \
        acc2[0] += w2_ * (f32x2)__builtin_amdgcn_cvt_pk_f32_fp8((int)(h).x, false); \
        acc2[1] += w2_ * (f32x2)__builtin_amdgcn_cvt_pk_f32_fp8((int)(h).x, true);  \
        acc2[2] += w2_ * (f32x2)__builtin_amdgcn_cvt_pk_f32_fp8((int)(h).y, false); \
        acc2[3] += w2_ * (f32x2)__builtin_amdgcn_cvt_pk_f32_fp8((int)(h).y, true);  \
    }

    int j = 0;
    for (; j + 3 < cnt; j += 4) {
        const int s0 = sp[j];
        const int s1 = sp[j + 1];
        const int s2 = sp[j + 2];
        const int s3 = sp[j + 3];
        const float w0 = __uint_as_float((uint32_t)wp[(size_t)(j + 0) * 8] << 16);
        const float w1 = __uint_as_float((uint32_t)wp[(size_t)(j + 1) * 8] << 16);
        const float w2 = __uint_as_float((uint32_t)wp[(size_t)(j + 2) * 8] << 16);
        const float w3 = __uint_as_float((uint32_t)wp[(size_t)(j + 3) * 8] << 16);
        const uint2 h0 = *(const uint2*)(H8 + (size_t)s0 * 512 + loff);
        const uint2 h1 = *(const uint2*)(H8 + (size_t)s1 * 512 + loff);
        const uint2 h2 = *(const uint2*)(H8 + (size_t)s2 * 512 + loff);
        const uint2 h3 = *(const uint2*)(H8 + (size_t)s3 * 512 + loff);
        ACCUM(w0, h0); ACCUM(w1, h1); ACCUM(w2, h2); ACCUM(w3, h3);
    }
    for (; j < cnt; ++j) {
        const int s0 = sp[j];
        const float w0 = __uint_as_float((uint32_t)wp[(size_t)j * 8] << 16);
        const uint2 h0 = *(const uint2*)(H8 + (size_t)s0 * 512 + loff);
        ACCUM(w0, h0);
    }
#undef ACCUM

    float accf[8] = {acc2[0].x, acc2[0].y, acc2[1].x, acc2[1].y,
                     acc2[2].x, acc2[2].y, acc2[3].x, acc2[3].y};
    #pragma unroll
    for (int k = 0; k < 8; ++k) {
        float v = accf[k];
        v += __shfl_xor(v, 8, 64);
        v += __shfl_xor(v, 16, 64);
        v += __shfl_xor(v, 32, 64);
        accf[k] = v;
    }
    if (sidx == 0) {
        const float inv = 1.f / fmaxf((float)cnt, 1.f);
        const size_t base = (size_t)n * 64 + cog * 8;
        const float4 r0 = *(const float4*)&Hroot[base];
        const float4 r1 = *(const float4*)&Hroot[base + 4];
        float vv[8];
        vv[0] = accf[0] * inv + r0.x; vv[1] = accf[1] * inv + r0.y;
        vv[2] = accf[2] * inv + r0.z; vv[3] = accf[3] * inv + r0.w;
        vv[4] = accf[4] * inv + r1.x; vv[5] = accf[5] * inv + r1.y;
        vv[6] = accf[6] * inv + r1.z; vv[7] = accf[7] * inv + r1.w;
        *(float4*)&outb[base]     = make_float4(vv[0], vv[1], vv[2], vv[3]);
        *(float4*)&outb[base + 4] = make_float4(vv[4], vv[5], vv[6], vv[7]);
        // conflict-free: iteration k -> 8 lanes write 8 consecutive floats
        #pragma unroll
        for (int k = 0; k < 8; ++k) {
            red_s[w][k * 8 + cog] = vv[k];
            red_q[w][k * 8 + cog] = vv[k] * vv[k];
        }
    }
    __syncthreads();
    if (t < 64) {
        const float s = red_s[0][t] + red_s[1][t] + red_s[2][t] + red_s[3][t];
        const float q = red_q[0][t] + red_q[1][t] + red_q[2][t] + red_q[3][t];
        const int co = (t & 7) * 8 + (t >> 3);   // inverse of k*8+cog mapping
        const int slot = (blockIdx.x & 63) * 64 + co;
        atomicAdd(&bnps[slot], s);
        atomicAdd(&bnpq[slot], q);
    }
}

// ---------------------------------------------------------------------------
// K3: BN + ELU. Stats preamble reduces the 64-slot partials per block.
// ---------------------------------------------------------------------------
__global__ __launch_bounds__(256) void finalize_kernel(float* __restrict__ outb,
                                                       const float* __restrict__ bnps,
                                                       const float* __restrict__ bnpq,
                                                       const float* __restrict__ gamma,
                                                       const float* __restrict__ beta) {
    __shared__ float sc_sh[64], sh_sh[64];
    const int t = threadIdx.x;
    if (t < 64) {
        float s = 0.f, q = 0.f;
        for (int k = 0; k < 64; ++k) { s += bnps[k * 64 + t]; q += bnpq[k * 64 + t]; }
        const float mean = s * (1.f / NN);
        const float var  = q * (1.f / NN) - mean * mean;
        const float sc = rsqrtf(var + EPS) * gamma[t];
        sc_sh[t] = sc;
        sh_sh[t] = beta[t] - mean * sc;
    }
    __syncthreads();
    const int total4 = NN * 16;
    for (int idx = blockIdx.x * 256 + t; idx < total4; idx += gridDim.x * 256) {
        float4 v = ((const float4*)outb)[idx];
        const int co0 = (idx & 15) * 4;
        float o[4] = {v.x, v.y, v.z, v.w};
        #pragma unroll
        for (int j = 0; j < 4; ++j) {
            const float y = o[j] * sc_sh[co0 + j] + sh_sh[co0 + j];
            o[j] = (y > 0.f) ? y : expm1f(y);
        }
        ((float4*)outb)[idx] = make_float4(o[0], o[1], o[2], o[3]);
    }
}

// ---------------------------------------------------------------------------
extern "C" void kernel_launch(void* const* d_in, const int* in_sizes, int n_in,
                              void* d_out, int out_size, void* d_ws, size_t ws_size,
                              hipStream_t stream) {
    const float* x     = (const float*)d_in[0];
    const float* attr  = (const float*)d_in[1];
    const float* W     = (const float*)d_in[2];
    const float* root  = (const float*)d_in[3];
    const float* gamma = (const float*)d_in[4];
    const float* beta  = (const float*)d_in[5];
    const int*   ei    = (const int*)d_in[6];
    float* outb = (float*)d_out;

    char* ws = (char*)d_ws;
    uint8_t* H8    = (uint8_t*)(ws);
    float*   Hroot = (float*)(ws + 25600000);
    int*     esrc  = (int*)(ws + 38400000);
    ushort*  ew8h  = (ushort*)(ws + 41600000);
    int*     offs  = (int*)(ws + 54400000);
    int*     part  = (int*)(ws + 54600064);
    float*   bnps  = (float*)(ws + 54600192);
    float*   bnpq  = (float*)(ws + 54616576);
    ushort*  WTg   = (ushort*)(ws + 54632960);
    int*     deg   = (int*)(ws + 54706688);

    void* cargs[] = {(void*)&ei, (void*)&attr, (void*)&W, (void*)&root,
                     (void*)&WTg, (void*)&deg, (void*)&offs, (void*)&part,
                     (void*)&esrc, (void*)&ew8h, (void*)&bnps, (void*)&bnpq};
    hipLaunchCooperativeKernel((void*)coop_k, dim3(NBC), dim3(NTC), cargs, 0, stream);

    mfma_k<<<NB_MFMA, 256, 0, stream>>>(x, WTg, H8, Hroot);
    aggregate_k<<<NN / 4, 256, 0, stream>>>(offs, esrc, ew8h, H8, Hroot, outb, bnps, bnpq);
    finalize_kernel<<<256, 256, 0, stream>>>(outb, bnps, bnpq, gamma, beta);
}

// Round 12
// 167.822 us; speedup vs baseline: 3.2598x; 3.2598x over previous
//
#include <hip/hip_runtime.h>
#include <hip/hip_bf16.h>
#include <cstdint>
#include <cstddef>

#define NN 50000
#define NE 800000
#define EPS 1e-5f

typedef short bf16x8 __attribute__((ext_vector_type(8)));
typedef float f32x4  __attribute__((ext_vector_type(4)));
typedef float f32x2  __attribute__((ext_vector_type(2)));

// ---------------- ws layout (bytes) ----------------
// H8    :          0   25,600,000  uchar   H[n][s][co] fp8 e4m3
// HROOTB: 25,600,000    6,400,000  ushort  (x@root)[n][co] bf16
// RECS  : 32,000,000    6,400,000  int2    {src, q3} dst-sorted
// RANK  : 38,400,000    3,200,000  int     rank of edge within its dst
// OFFS  : 41,600,000      200,000  int     block-local CSR offsets [NN]
// DEG   : 41,800,000      200,000  int     degree histogram   \ memset
// PART  : 42,000,000          128  int     scan partials      / together
// BNPS  : 42,000,128       16,384  float   BN sum partials  (zeroed in K0)
// BNPQ  : 42,016,512       16,384  float   BN ssq partials  (zeroed in K0)
// WTG   : 42,032,896       73,728  ushort  WTg[s][co][ci] bf16 (s=8 is root)

#define NB_WT   144    // 9*4096/256
#define NB_CNT  3125   // ceil(NE/256)
#define NB_MFMA 782
#define NB_SCAN 25

static __device__ __forceinline__ ushort f2bf(float f) {
    __hip_bfloat16 h = __float2bfloat16(f);
    return *reinterpret_cast<ushort*>(&h);
}
static __device__ __forceinline__ float bf_lo(uint32_t u) {
    return __uint_as_float(u << 16);
}
static __device__ __forceinline__ float bf_hi(uint32_t u) {
    return __uint_as_float(u & 0xffff0000u);
}
static __device__ __forceinline__ uint32_t pack2(float a, float b) {
    return (uint32_t)f2bf(a) | ((uint32_t)f2bf(b) << 16);
}

// ---------------------------------------------------------------------------
// K0 (fused): blocks [0,144): W(+root) transpose -> WTg bf16, + zero bn
//             partials. blocks [144, 144+3125): degree histogram + rank.
// ---------------------------------------------------------------------------
__global__ __launch_bounds__(256) void prep_count_k(const float* __restrict__ W,
                                                    const float* __restrict__ root,
                                                    ushort* __restrict__ WTg,
                                                    const int* __restrict__ ei,
                                                    int* __restrict__ deg,
                                                    int* __restrict__ rank,
                                                    float* __restrict__ bnps,
                                                    float* __restrict__ bnpq) {
    const int b = blockIdx.x;
    if (b < NB_WT) {
        const int idx = b * 256 + threadIdx.x;           // [0, 9*4096)
        const int s  = idx >> 12;
        const int co = (idx >> 6) & 63;
        const int ci = idx & 63;
        const float v = (s < 8) ? W[s * 4096 + ci * 64 + co] : root[ci * 64 + co];
        WTg[idx] = f2bf(v);                              // WTg[s][co][ci]
        if (idx < 4096) { bnps[idx] = 0.f; bnpq[idx] = 0.f; }
    } else {
        const int e = (b - NB_WT) * 256 + threadIdx.x;
        if (e < NE) rank[e] = atomicAdd(&deg[ei[NE + e]], 1);
    }
}

// ---------------------------------------------------------------------------
// K1 (fused): blocks [0,782): MFMA GEMM -> H8 (fp8) / HROOTB (bf16).
//   XA staged ONCE; WT restaged in place between the two s-halves.
//   blocks [782,807): scan1 (block-local excl scan of deg).
// MFMA 16x16x32 bf16, swapped operands (D row-dim = co, col-dim = node).
// ---------------------------------------------------------------------------
__global__ __launch_bounds__(256) void mfma_scan_k(
        const float* __restrict__ x, const ushort* __restrict__ WTg,
        uint8_t* __restrict__ H8, ushort* __restrict__ Hrootb,
        const int* __restrict__ deg, int* __restrict__ offs,
        int* __restrict__ part) {
    __shared__ __align__(16) ushort XA[64 * 64];       // 8 KB
    __shared__ __align__(16) ushort WT[5 * 64 * 64];   // 40 KB
    __shared__ int sh[256];
    const int t = threadIdx.x;
    const int b = blockIdx.x;

    if (b >= NB_MFMA) {                    // ---- scan path ----
        const int sb = b - NB_MFMA;
        const int base = sb * 2048 + t * 8;
        int v[8]; int sum = 0;
        #pragma unroll
        for (int k = 0; k < 8; ++k) {
            int i = base + k;
            int d = (i < NN) ? deg[i] : 0;
            v[k] = sum; sum += d;
        }
        sh[t] = sum; __syncthreads();
        for (int off = 1; off < 256; off <<= 1) {
            int val = sh[t];
            int add = (t >= off) ? sh[t - off] : 0;
            __syncthreads();
            sh[t] = val + add;
            __syncthreads();
        }
        int excl = (t > 0) ? sh[t - 1] : 0;
        #pragma unroll
        for (int k = 0; k < 8; ++k) {
            int i = base + k;
            if (i < NN) offs[i] = excl + v[k];
        }
        if (t == 255) part[sb] = sh[255];
        return;
    }

    // ---- MFMA path ----
    const int n0 = b * 64;

    // stage XA[node][ci] bf16, XOR-swizzled, b128 writes (once)
    #pragma unroll
    for (int rep = 0; rep < 2; ++rep) {
        const int vt   = rep * 256 + t;
        const int row  = vt >> 3;          // node local 0..63
        const int col8 = vt & 7;
        const int n = n0 + row;
        uint4 u;
        if (n < NN) {
            const float4 v0 = *(const float4*)&x[(size_t)n * 64 + col8 * 8];
            const float4 v1 = *(const float4*)&x[(size_t)n * 64 + col8 * 8 + 4];
            u.x = pack2(v0.x, v0.y); u.y = pack2(v0.z, v0.w);
            u.z = pack2(v1.x, v1.y); u.w = pack2(v1.z, v1.w);
        } else {
            u = make_uint4(0, 0, 0, 0);
        }
        const int idx = (row * 64 + col8 * 8) ^ ((row & 7) << 3);
        *(uint4*)&XA[idx] = u;
    }

    const int w    = t >> 6;
    const int lane = t & 63;
    const int mrow = lane & 15;
    const int kgrp = lane >> 4;
    const int swz  = (mrow & 7) << 3;
    const int arow = w * 16 + mrow;
    const int n    = n0 + arow;
    bf16x8 a0, a1;

    for (int pass = 0; pass < 2; ++pass) {
        const int sbeg   = pass ? 5 : 0;
        const int scount = pass ? 4 : 5;
        // stage WT tiles [sbeg, sbeg+scount): b128 copies, swizzled
        const int nchunk = scount * 512;                 // uint4 chunks
        for (int c = t; c < nchunk; c += 256) {
            const int row  = c >> 3;       // slocal*64 + co
            const int col8 = c & 7;
            const uint4 u = *(const uint4*)&WTg[(size_t)(sbeg * 64 + row) * 64 + col8 * 8];
            const int idx = (row * 64 + col8 * 8) ^ ((row & 7) << 3);
            *(uint4*)&WT[idx] = u;
        }
        __syncthreads();
        if (pass == 0) {
            a0 = *(const bf16x8*)&XA[((arow * 64) + 0 * 32 + kgrp * 8) ^ swz];
            a1 = *(const bf16x8*)&XA[((arow * 64) + 1 * 32 + kgrp * 8) ^ swz];
        }
        for (int sl = 0; sl < scount; ++sl) {
            const int s = sbeg + sl;
            const ushort* wt = &WT[sl * 4096];
            f32x4 acc[4];
            #pragma unroll
            for (int ct = 0; ct < 4; ++ct) {
                acc[ct] = (f32x4){0.f, 0.f, 0.f, 0.f};
                const int brow = ct * 16 + mrow;
                const bf16x8 b0 = *(const bf16x8*)&wt[((brow * 64) + 0 * 32 + kgrp * 8) ^ swz];
                const bf16x8 b1 = *(const bf16x8*)&wt[((brow * 64) + 1 * 32 + kgrp * 8) ^ swz];
                acc[ct] = __builtin_amdgcn_mfma_f32_16x16x32_bf16(b0, a0, acc[ct], 0, 0, 0);
                acc[ct] = __builtin_amdgcn_mfma_f32_16x16x32_bf16(b1, a1, acc[ct], 0, 0, 0);
            }
            if (n < NN) {
                if (s < 8) {
                    #pragma unroll
                    for (int ct = 0; ct < 4; ++ct) {
                        int p = __builtin_amdgcn_cvt_pk_fp8_f32(acc[ct][0], acc[ct][1], 0, false);
                        p     = __builtin_amdgcn_cvt_pk_fp8_f32(acc[ct][2], acc[ct][3], p, true);
                        *(uint32_t*)&H8[(size_t)n * 512 + s * 64 + ct * 16 + kgrp * 4] = (uint32_t)p;
                    }
                } else {
                    #pragma unroll
                    for (int ct = 0; ct < 4; ++ct) {
                        ushort4 h4;
                        h4.x = f2bf(acc[ct][0]); h4.y = f2bf(acc[ct][1]);
                        h4.z = f2bf(acc[ct][2]); h4.w = f2bf(acc[ct][3]);
                        *(ushort4*)&Hrootb[(size_t)n * 64 + ct * 16 + kgrp * 4] = h4;
                    }
                }
            }
        }
        __syncthreads();   // drain WT reads before pass-1 restage
    }
}

// ---------------------------------------------------------------------------
// K2: scatter edges (no atomics): p = offs[dst] + ppre[dst>>11] + rank[e].
// record = {src, q3}, q3 = 3x10-bit quantized fracs (8 B random writes).
// ---------------------------------------------------------------------------
__global__ __launch_bounds__(256) void scatter_k(const int* __restrict__ ei,
                                                 const float* __restrict__ attr,
                                                 const int* __restrict__ offs,
                                                 const int* __restrict__ part,
                                                 const int* __restrict__ rank,
                                                 int2* __restrict__ recs) {
    __shared__ int pp[25];
    const int t = threadIdx.x;
    if (t < 25) pp[t] = part[t];
    __syncthreads();
    if (t == 0) {
        int s = 0;
        #pragma unroll
        for (int i = 0; i < 25; ++i) { int v = pp[i]; pp[i] = s; s += v; }
    }
    __syncthreads();
    int e = blockIdx.x * 256 + t;
    if (e >= NE) return;
    const int src = ei[e];
    const int dst = ei[NE + e];
    const float f0 = attr[(size_t)e * 3 + 0];
    const float f1 = attr[(size_t)e * 3 + 1];
    const float f2 = attr[(size_t)e * 3 + 2];
    const uint32_t q = (uint32_t)rintf(f0 * 1023.f)
                     | ((uint32_t)rintf(f1 * 1023.f) << 10)
                     | ((uint32_t)rintf(f2 * 1023.f) << 20);
    const int p = offs[dst] + pp[dst >> 11] + rank[e];
    recs[p] = make_int2(src, (int)q);
}

// ---------------------------------------------------------------------------
// K3: gather-aggregate (fp8 H) + fused BN partials. One node per wave.
// lane l: s=l>>3, co=(l&7)*8..+8 -> one dwordx2 (8 fp8) per edge per lane.
// ---------------------------------------------------------------------------
__global__ __launch_bounds__(256) void aggregate_k(const int* __restrict__ offs,
                                                   const int* __restrict__ part,
                                                   const int* __restrict__ deg,
                                                   const int2* __restrict__ recs,
                                                   const uint8_t* __restrict__ H8,
                                                   const ushort* __restrict__ Hrootb,
                                                   float* __restrict__ outb,
                                                   float* __restrict__ bnps,
                                                   float* __restrict__ bnpq) {
    __shared__ int pp[25];
    __shared__ float red_s[4][64], red_q[4][64];
    const int t = threadIdx.x, lane = t & 63, w = t >> 6;
    if (t < 25) pp[t] = part[t];
    __syncthreads();
    if (t == 0) {
        int s = 0;
        #pragma unroll
        for (int i = 0; i < 25; ++i) { int v = pp[i]; pp[i] = s; s += v; }
    }
    __syncthreads();

    const int n = blockIdx.x * 4 + w;            // NN = 4*12500, no tail
    const int sidx = lane >> 3;
    const int cog  = lane & 7;
    const float sg0 = (sidx & 1) ? 1.f : -1.f, cc0 = (sidx & 1) ? 0.f : 1.f;
    const float sg1 = (sidx & 2) ? 1.f : -1.f, cc1 = (sidx & 2) ? 0.f : 1.f;
    const float sg2 = (sidx & 4) ? 1.f : -1.f, cc2 = (sidx & 4) ? 0.f : 1.f;
    const int cnt = deg[n];
    const int beg = offs[n] + pp[n >> 11];
    const int2* rp = recs + beg;
    const size_t loff = (size_t)(lane << 3);     // byte offset: s*64 + cog*8

    f32x2 acc2[4] = {(f32x2){0.f, 0.f}, (f32x2){0.f, 0.f},
                     (f32x2){0.f, 0.f}, (f32x2){0.f, 0.f}};

#define DECODE_W(qv, wv)                                                     \
    {                                                                        \
        const uint32_t q_ = (uint32_t)(qv);                                  \
        const float f0_ = (float)(q_ & 1023u) * (1.f / 1023.f);              \
        const float f1_ = (float)((q_ >> 10) & 1023u) * (1.f / 1023.f);      \
        const float f2_ = (float)((q_ >> 20) & 1023u) * (1.f / 1023.f);      \
        wv = (cc0 + sg0 * f0_) * ((cc1 + sg1 * f1_) * (cc2 + sg2 * f2_));    \
    }
#define ACCUM(wv, h)                                                         \
    {                                                                        \
        const f32x2 w2_ = {wv, wv};                                          \
        acc2[0] += w2_ * (f32x2)__builtin_amdgcn_cvt_pk_f32_fp8((int)(h).x, false); \
        acc2[1] += w2_ * (f32x2)__builtin_amdgcn_cvt_pk_f32_fp8((int)(h).x, true);  \
        acc2[2] += w2_ * (f32x2)__builtin_amdgcn_cvt_pk_f32_fp8((int)(h).y, false); \
        acc2[3] += w2_ * (f32x2)__builtin_amdgcn_cvt_pk_f32_fp8((int)(h).y, true);  \
    }

    int j = 0;
    for (; j + 3 < cnt; j += 4) {
        const int2 r0 = rp[j];
        const int2 r1 = rp[j + 1];
        const int2 r2 = rp[j + 2];
        const int2 r3 = rp[j + 3];
        const uint2 h0 = *(const uint2*)(H8 + (size_t)r0.x * 512 + loff);
        const uint2 h1 = *(const uint2*)(H8 + (size_t)r1.x * 512 + loff);
        const uint2 h2 = *(const uint2*)(H8 + (size_t)r2.x * 512 + loff);
        const uint2 h3 = *(const uint2*)(H8 + (size_t)r3.x * 512 + loff);
        float w0, w1, w2, w3;
        DECODE_W(r0.y, w0); DECODE_W(r1.y, w1);
        DECODE_W(r2.y, w2); DECODE_W(r3.y, w3);
        ACCUM(w0, h0); ACCUM(w1, h1); ACCUM(w2, h2); ACCUM(w3, h3);
    }
    for (; j < cnt; ++j) {
        const int2 r0 = rp[j];
        const uint2 h0 = *(const uint2*)(H8 + (size_t)r0.x * 512 + loff);
        float w0;
        DECODE_W(r0.y, w0);
        ACCUM(w0, h0);
    }
#undef DECODE_W
#undef ACCUM

    float accf[8] = {acc2[0].x, acc2[0].y, acc2[1].x, acc2[1].y,
                     acc2[2].x, acc2[2].y, acc2[3].x, acc2[3].y};
    #pragma unroll
    for (int k = 0; k < 8; ++k) {
        float v = accf[k];
        v += __shfl_xor(v, 8, 64);
        v += __shfl_xor(v, 16, 64);
        v += __shfl_xor(v, 32, 64);
        accf[k] = v;
    }
    if (sidx == 0) {
        const float inv = 1.f / fmaxf((float)cnt, 1.f);
        const size_t base = (size_t)n * 64 + cog * 8;
        const uint4 hr = *(const uint4*)&Hrootb[base];
        const float rr[8] = {bf_lo(hr.x), bf_hi(hr.x), bf_lo(hr.y), bf_hi(hr.y),
                             bf_lo(hr.z), bf_hi(hr.z), bf_lo(hr.w), bf_hi(hr.w)};
        float vv[8];
        #pragma unroll
        for (int k = 0; k < 8; ++k) vv[k] = accf[k] * inv + rr[k];
        *(float4*)&outb[base]     = make_float4(vv[0], vv[1], vv[2], vv[3]);
        *(float4*)&outb[base + 4] = make_float4(vv[4], vv[5], vv[6], vv[7]);
        // conflict-free: iteration k -> 8 lanes write 8 consecutive floats
        #pragma unroll
        for (int k = 0; k < 8; ++k) {
            red_s[w][k * 8 + cog] = vv[k];
            red_q[w][k * 8 + cog] = vv[k] * vv[k];
        }
    }
    __syncthreads();
    if (t < 64) {
        const float s = red_s[0][t] + red_s[1][t] + red_s[2][t] + red_s[3][t];
        const float q = red_q[0][t] + red_q[1][t] + red_q[2][t] + red_q[3][t];
        const int co = (t & 7) * 8 + (t >> 3);   // inverse of k*8+cog mapping
        const int slot = (blockIdx.x & 63) * 64 + co;
        atomicAdd(&bnps[slot], s);
        atomicAdd(&bnpq[slot], q);
    }
}

// ---------------------------------------------------------------------------
// K4: BN + ELU. Stats preamble reduces the 64-slot partials per block.
// ---------------------------------------------------------------------------
__global__ __launch_bounds__(256) void finalize_kernel(float* __restrict__ outb,
                                                       const float* __restrict__ bnps,
                                                       const float* __restrict__ bnpq,
                                                       const float* __restrict__ gamma,
                                                       const float* __restrict__ beta) {
    __shared__ float sc_sh[64], sh_sh[64];
    const int t = threadIdx.x;
    if (t < 64) {
        float s = 0.f, q = 0.f;
        for (int k = 0; k < 64; ++k) { s += bnps[k * 64 + t]; q += bnpq[k * 64 + t]; }
        const float mean = s * (1.f / NN);
        const float var  = q * (1.f / NN) - mean * mean;
        const float sc = rsqrtf(var + EPS) * gamma[t];
        sc_sh[t] = sc;
        sh_sh[t] = beta[t] - mean * sc;
    }
    __syncthreads();
    const int total4 = NN * 16;
    for (int idx = blockIdx.x * 256 + t; idx < total4; idx += gridDim.x * 256) {
        float4 v = ((const float4*)outb)[idx];
        const int co0 = (idx & 15) * 4;
        float o[4] = {v.x, v.y, v.z, v.w};
        #pragma unroll
        for (int j = 0; j < 4; ++j) {
            const float y = o[j] * sc_sh[co0 + j] + sh_sh[co0 + j];
            o[j] = (y > 0.f) ? y : expm1f(y);
        }
        ((float4*)outb)[idx] = make_float4(o[0], o[1], o[2], o[3]);
    }
}

// ---------------------------------------------------------------------------
extern "C" void kernel_launch(void* const* d_in, const int* in_sizes, int n_in,
                              void* d_out, int out_size, void* d_ws, size_t ws_size,
                              hipStream_t stream) {
    const float* x     = (const float*)d_in[0];
    const float* attr  = (const float*)d_in[1];
    const float* W     = (const float*)d_in[2];
    const float* root  = (const float*)d_in[3];
    const float* gamma = (const float*)d_in[4];
    const float* beta  = (const float*)d_in[5];
    const int*   ei    = (const int*)d_in[6];
    float* outb = (float*)d_out;

    char* ws = (char*)d_ws;
    uint8_t* H8     = (uint8_t*)(ws);
    ushort*  Hrootb = (ushort*)(ws + 25600000);
    int2*    recs   = (int2*)(ws + 32000000);
    int*     rank   = (int*)(ws + 38400000);
    int*     offs   = (int*)(ws + 41600000);
    int*     deg    = (int*)(ws + 41800000);
    int*     part   = (int*)(ws + 42000000);
    float*   bnps   = (float*)(ws + 42000128);
    float*   bnpq   = (float*)(ws + 42016512);
    ushort*  WTg    = (ushort*)(ws + 42032896);

    // zero deg + part (bn partials zeroed inside prep_count_k)
    hipMemsetAsync(ws + 41800000, 0, 200128, stream);

    prep_count_k<<<NB_WT + NB_CNT, 256, 0, stream>>>(W, root, WTg, ei, deg, rank, bnps, bnpq);
    mfma_scan_k<<<NB_MFMA + NB_SCAN, 256, 0, stream>>>(x, WTg, H8, Hrootb, deg, offs, part);
    scatter_k<<<NB_CNT, 256, 0, stream>>>(ei, attr, offs, part, rank, recs);
    aggregate_k<<<NN / 4, 256, 0, stream>>>(offs, part, deg, recs, H8, Hrootb, outb, bnps, bnpq);
    finalize_kernel<<<256, 256, 0, stream>>>(outb, bnps, bnpq, gamma, beta);
}